// Round 1
// baseline (143.945 us; speedup 1.0000x reference)
//
#include <hip/hip_runtime.h>
#include <hip/hip_bf16.h>

// Established: inputs f32, output f32. Threshold 0.038; absmax floor 0.0078 (1 bf16 ulp).
// Math: y = (rec + DELTA*(cat(du,u)@Bw^T)) @ Cw^T,  rec = h + 0.005*(W@h - W^T@h)
// (expm/inv series truncated at X^1; X^2+ terms <4e-5, validated r3-r9).
// r9 lesson: intra-kernel barrier/spin fusion catastrophically slow; 3-kernel skeleton kept.
// r11: k2/k3 were barrier-bound micro-tile LDS GEMMs (<=4 MFMA per syncthreads pair).
// Operands are L2/L3-resident (<=6.3 MB each) -> LDS staging was pure overhead (guide CM#7).
// New: barrier-free register-direct fragment GEMMs (32x32 tile per wave, 2x2 frags,
// per-lane 16B dwordx4 frag loads straight from global, SW-pipelined K-loop).
// cat(du,u) pre-converted to bf16 once in k1 (was re-read 32x as f32 + cvt in k2).

#define B_SZ 512
#define U_DIM 1024
#define DU_DIM 512
#define H_DIM 2048
#define Y_DIM 1024
#define K_CAT 1536
#define DELTA_F 0.01f

typedef __hip_bfloat16 bf16;
using bf16x8f = __attribute__((ext_vector_type(8))) short;
using f32x4   = __attribute__((ext_vector_type(4))) float;

__device__ __forceinline__ short f2bs(float x) {
  union { bf16 b; short s; } u; u.b = __float2bfloat16(x); return u.s;
}
__device__ __forceinline__ int4 pack8(const float4 v0, const float4 v1) {
  union { short s[8]; int4 i; } o;
  o.s[0] = f2bs(v0.x); o.s[1] = f2bs(v0.y); o.s[2] = f2bs(v0.z); o.s[3] = f2bs(v0.w);
  o.s[4] = f2bs(v1.x); o.s[5] = f2bs(v1.y); o.s[6] = f2bs(v1.z); o.s[7] = f2bs(v1.w);
  return o.i;
}

#define NB   (H_DIM * K_CAT / 8)   // 393216 Bw granules
#define NCAT (B_SZ * K_CAT / 8)    //  98304 cat granules
#define NC   (Y_DIM * H_DIM / 8)   // 262144 Cw granules

// ---------------- K1: wh (0..511), wtp partials (512..767), Bw+cat cvt (768..1023) ----------------
__global__ __launch_bounds__(256) void k1(const float* __restrict__ W, const float* __restrict__ h,
                                          const float* __restrict__ Bw, const float* __restrict__ du,
                                          const float* __restrict__ u, float* __restrict__ wh,
                                          float* __restrict__ wtp, short* __restrict__ Bwb,
                                          short* __restrict__ catb) {
  const int b = blockIdx.x;
  if (b < 512) {  // wh[row] = dot(W[row,:], h)
    const int lane = threadIdx.x & 63, wave = threadIdx.x >> 6;
    const int row = b * 4 + wave;
    const float* wr = W + (size_t)row * H_DIM;
    float s = 0.f;
#pragma unroll
    for (int it = 0; it < 8; it++) {
      int k = it * 256 + lane * 4;
      float4 a = *(const float4*)(wr + k);
      float4 hv = *(const float4*)(h + k);
      s += a.x * hv.x + a.y * hv.y + a.z * hv.z + a.w * hv.w;
    }
#pragma unroll
    for (int off = 32; off > 0; off >>= 1) s += __shfl_down(s, off);
    if (lane == 0) wh[row] = s;
  } else if (b < 768) {  // wtp[rowg][k] = sum over 64-row chunk of W[i][k]*h[i]
    const int e = b - 512;
    const int colg = e & 7, rowg = e >> 3;
    const int k = colg * 256 + threadIdx.x;
    float s = 0.f;
    const float* base = W + (size_t)rowg * 64 * H_DIM + k;
#pragma unroll 8
    for (int i = 0; i < 64; i++) s += base[(size_t)i * H_DIM] * h[rowg * 64 + i];
    wtp[rowg * H_DIM + k] = s;
  } else {  // Bw -> bf16 ; cat(du,u) -> bf16
    for (int g = (b - 768) * 256 + threadIdx.x; g < NB + NCAT; g += 256 * 256) {
      if (g < NB) {
        int e = g * 8;
        *(int4*)(Bwb + e) = pack8(*(const float4*)(Bw + e), *(const float4*)(Bw + e + 4));
      } else {
        int g2 = g - NB;
        int row = g2 / 192, c = g2 - row * 192;  // 192 granules per 1536-wide row
        const float* src = (c < 64) ? du + (size_t)row * DU_DIM + c * 8
                                    : u + (size_t)row * U_DIM + (c - 64) * 8;
        *(int4*)(catb + (size_t)row * K_CAT + c * 8) =
            pack8(*(const float4*)src, *(const float4*)(src + 4));
      }
    }
  }
}

// ---- barrier-free per-wave 32x32 GEMM core: acc[4] = A[32xK] @ B[32xK]^T fragments ----
// A,B row-major [rows][KDIM] bf16; lane rm=lane&15 picks row, quad=(lane>>4) picks 8-elem k-slot.
#define MFMA __builtin_amdgcn_mfma_f32_16x16x32_bf16
template <int KDIM>
__device__ __forceinline__ void gemm_wave(const short* __restrict__ A, const short* __restrict__ B,
                                          int row0, int col0, int rm, int kq, f32x4* acc) {
  const short* pa0 = A + (size_t)(row0 + rm) * KDIM + kq;
  const short* pa1 = pa0 + (size_t)16 * KDIM;
  const short* pb0 = B + (size_t)(col0 + rm) * KDIM + kq;
  const short* pb1 = pb0 + (size_t)16 * KDIM;
  constexpr int NS = KDIM / 32;  // K-steps of 32
  bf16x8f a0 = *(const bf16x8f*)(pa0),      a1 = *(const bf16x8f*)(pa1);
  bf16x8f b0 = *(const bf16x8f*)(pb0),      b1 = *(const bf16x8f*)(pb1);
  bf16x8f a2 = *(const bf16x8f*)(pa0 + 32), a3 = *(const bf16x8f*)(pa1 + 32);
  bf16x8f b2 = *(const bf16x8f*)(pb0 + 32), b3 = *(const bf16x8f*)(pb1 + 32);
#pragma unroll 2
  for (int kt = 2; kt < NS; kt += 2) {
    const int o = kt * 32;
    bf16x8f na0 = *(const bf16x8f*)(pa0 + o),      na1 = *(const bf16x8f*)(pa1 + o);
    bf16x8f nb0 = *(const bf16x8f*)(pb0 + o),      nb1 = *(const bf16x8f*)(pb1 + o);
    bf16x8f na2 = *(const bf16x8f*)(pa0 + o + 32), na3 = *(const bf16x8f*)(pa1 + o + 32);
    bf16x8f nb2 = *(const bf16x8f*)(pb0 + o + 32), nb3 = *(const bf16x8f*)(pb1 + o + 32);
    acc[0] = MFMA(a0, b0, acc[0], 0, 0, 0); acc[1] = MFMA(a0, b1, acc[1], 0, 0, 0);
    acc[2] = MFMA(a1, b0, acc[2], 0, 0, 0); acc[3] = MFMA(a1, b1, acc[3], 0, 0, 0);
    acc[0] = MFMA(a2, b2, acc[0], 0, 0, 0); acc[1] = MFMA(a2, b3, acc[1], 0, 0, 0);
    acc[2] = MFMA(a3, b2, acc[2], 0, 0, 0); acc[3] = MFMA(a3, b3, acc[3], 0, 0, 0);
    a0 = na0; a1 = na1; b0 = nb0; b1 = nb1;
    a2 = na2; a3 = na3; b2 = nb2; b3 = nb3;
  }
  acc[0] = MFMA(a0, b0, acc[0], 0, 0, 0); acc[1] = MFMA(a0, b1, acc[1], 0, 0, 0);
  acc[2] = MFMA(a1, b0, acc[2], 0, 0, 0); acc[3] = MFMA(a1, b1, acc[3], 0, 0, 0);
  acc[0] = MFMA(a2, b2, acc[0], 0, 0, 0); acc[1] = MFMA(a2, b3, acc[1], 0, 0, 0);
  acc[2] = MFMA(a3, b2, acc[2], 0, 0, 0); acc[3] = MFMA(a3, b3, acc[3], 0, 0, 0);
}

// ---------------- K2: 256 GEMM blocks (1024 waves, 16x64 tiles) + 128 Cw-cvt blocks ----------------
// bb[r][c] = bf16(rec[c] + DELTA * (catb[32xK] @ Bwb[32xK]^T)),  rec per-lane from wh/wtp/h.
__global__ __launch_bounds__(256) void k2(const short* __restrict__ catb, const short* __restrict__ Bwb,
                                          const float* __restrict__ h, const float* __restrict__ wh,
                                          const float* __restrict__ wtp, short* __restrict__ bb,
                                          const float* __restrict__ Cw, short* __restrict__ Cwb) {
  const int b = blockIdx.x;
  if (b < 256) {
    const int lane = threadIdx.x & 63, wave = threadIdx.x >> 6;
    const int t = b * 4 + wave;          // 1024 tiles: 16 mt x 64 nt (block's 4 waves share mt/A-panel)
    const int mt = t >> 6, nt = t & 63;
    const int row0 = mt * 32, col0 = nt * 32;
    const int rm = lane & 15, quad = lane >> 4, kq = quad * 8;
    f32x4 acc[4] = {};
    gemm_wave<K_CAT>(catb, Bwb, row0, col0, rm, kq, acc);
    float recv[2];
#pragma unroll
    for (int j = 0; j < 2; j++) {  // rec[c] = h[c] + 0.005*(wh[c] - sum_p wtp[p][c])
      int c = col0 + 16 * j + rm;
      float s = 0.f;
#pragma unroll
      for (int p = 0; p < 32; p++) s += wtp[p * H_DIM + c];
      recv[j] = h[c] + 0.005f * (wh[c] - s);
    }
#pragma unroll
    for (int i = 0; i < 2; i++)
#pragma unroll
      for (int j = 0; j < 2; j++)
#pragma unroll
        for (int r = 0; r < 4; r++) {
          int gr = row0 + 16 * i + quad * 4 + r;
          int gc = col0 + 16 * j + rm;
          bb[(size_t)gr * H_DIM + gc] = f2bs(recv[j] + DELTA_F * acc[i * 2 + j][r]);
        }
  } else {  // Cw -> bf16 (consumed only by k3; overlaps GEMM waves)
    int g0 = (b - 256) * 256 + threadIdx.x;  // 32768 threads x 8 granules = NC
#pragma unroll
    for (int it = 0; it < 8; it++) {
      int e = (g0 + it * 32768) * 8;
      *(int4*)(Cwb + e) = pack8(*(const float4*)(Cw + e), *(const float4*)(Cw + e + 4));
    }
  }
}

// ---------------- K3: 128 blocks (512 waves, 16x32 tiles): y = bb @ Cwb^T (f32 out) ----------------
__global__ __launch_bounds__(256) void k3(const short* __restrict__ A, const short* __restrict__ B,
                                          float* __restrict__ y) {
  const int lane = threadIdx.x & 63, wave = threadIdx.x >> 6;
  const int t = blockIdx.x * 4 + wave;  // 512 tiles: 16 mt x 32 nt
  const int mt = t >> 5, nt = t & 31;
  const int row0 = mt * 32, col0 = nt * 32;
  const int rm = lane & 15, quad = lane >> 4, kq = quad * 8;
  f32x4 acc[4] = {};
  gemm_wave<H_DIM>(A, B, row0, col0, rm, kq, acc);
#pragma unroll
  for (int i = 0; i < 2; i++)
#pragma unroll
    for (int j = 0; j < 2; j++)
#pragma unroll
      for (int r = 0; r < 4; r++) {
        int gr = row0 + 16 * i + quad * 4 + r;
        int gc = col0 + 16 * j + rm;
        y[(size_t)gr * Y_DIM + gc] = acc[i * 2 + j][r];
      }
}

extern "C" void kernel_launch(void* const* d_in, const int* in_sizes, int n_in,
                              void* d_out, int out_size, void* d_ws, size_t ws_size,
                              hipStream_t stream) {
  const float* u  = (const float*)d_in[0];
  const float* du = (const float*)d_in[1];
  const float* W  = (const float*)d_in[2];
  const float* Bw = (const float*)d_in[3];
  const float* Cw = (const float*)d_in[4];
  const float* h  = (const float*)d_in[5];
  float* y = (float*)d_out;

  char* w = (char*)d_ws;
  size_t off = 0;
  short* Bwb  = (short*)(w + off); off += (size_t)H_DIM * K_CAT * sizeof(short);  // 6 MB
  short* Cwb  = (short*)(w + off); off += (size_t)Y_DIM * H_DIM * sizeof(short);  // 4 MB
  short* bb   = (short*)(w + off); off += (size_t)B_SZ * H_DIM * sizeof(short);   // 2 MB
  short* catb = (short*)(w + off); off += (size_t)B_SZ * K_CAT * sizeof(short);   // 1.5 MB
  float* wh   = (float*)(w + off); off += H_DIM * sizeof(float);
  float* wtp  = (float*)(w + off); off += 32 * H_DIM * sizeof(float);
  if (ws_size < off) return;

  k1<<<1024, 256, 0, stream>>>(W, h, Bw, du, u, wh, wtp, Bwb, catb);
  k2<<<384, 256, 0, stream>>>(catb, Bwb, h, wh, wtp, bb, Cw, Cwb);
  k3<<<128, 256, 0, stream>>>(bb, Cwb, y);
}

// Round 2
// 128.679 us; speedup vs baseline: 1.1186x; 1.1186x over previous
//
#include <hip/hip_runtime.h>
#include <hip/hip_bf16.h>

// Established: inputs f32, output f32. Threshold 0.038; absmax floor 0.0078 (1 bf16 ulp).
// Math: y = (rec + DELTA*(cat(du,u)@Bw^T)) @ Cw^T,  rec = h + 0.005*(W@h - W^T@h)
// (expm/inv series truncated at X^1; X^2+ terms <4e-5, validated r3-r9).
// r9: intra-kernel fusion catastrophic. r11 (reg-direct, 384/128 blocks): REGRESSED +21us
//   -> low occupancy (1 wave/SIMD) + 1-deep prefetch cannot hide L2/L3 latency.
// r12: r0 grid shape restored (k2=1024, k3=512 GEMM blocks, 2-phase LDS dbuf) with
//   staging upgraded to global_load_lds width=16 (no VGPR round-trip, no staging VALU)
//   + both-sides XOR granule swizzle (linear LDS dest mandated by gl_lds; rule #21).
//   k1 pre-converts Bw, cat(du,u), Cw to bf16 (gl_lds can't convert in flight).

#define B_SZ 512
#define U_DIM 1024
#define DU_DIM 512
#define H_DIM 2048
#define Y_DIM 1024
#define K_CAT 1536
#define DELTA_F 0.01f

typedef __hip_bfloat16 bf16;
using bf16x8f = __attribute__((ext_vector_type(8))) short;
using f32x4   = __attribute__((ext_vector_type(4))) float;

__device__ __forceinline__ short f2bs(float x) {
  union { bf16 b; short s; } u; u.b = __float2bfloat16(x); return u.s;
}
__device__ __forceinline__ int4 pack8(const float4 v0, const float4 v1) {
  union { short s[8]; int4 i; } o;
  o.s[0] = f2bs(v0.x); o.s[1] = f2bs(v0.y); o.s[2] = f2bs(v0.z); o.s[3] = f2bs(v0.w);
  o.s[4] = f2bs(v1.x); o.s[5] = f2bs(v1.y); o.s[6] = f2bs(v1.z); o.s[7] = f2bs(v1.w);
  return o.i;
}

// async 16B global->LDS. LDS dest is wave-uniform base + lane*16 (linear in tid).
__device__ __forceinline__ void stage16(const void* g, void* l) {
  __builtin_amdgcn_global_load_lds(
      (const __attribute__((address_space(1))) unsigned int*)g,
      (__attribute__((address_space(3))) unsigned int*)l, 16, 0, 0);
}

#define NB   (H_DIM * K_CAT / 8)   // 393216 Bw granules
#define NCAT (B_SZ * K_CAT / 8)    //  98304 cat granules
#define NC   (Y_DIM * H_DIM / 8)   // 262144 Cw granules
#define NTOT (NB + NCAT + NC)

// ---------------- K1: wh (0..511), wtp partials (512..767), all bf16 cvts (768..1023) ----------------
__global__ __launch_bounds__(256) void k1(const float* __restrict__ W, const float* __restrict__ h,
                                          const float* __restrict__ Bw, const float* __restrict__ du,
                                          const float* __restrict__ u, const float* __restrict__ Cw,
                                          float* __restrict__ wh, float* __restrict__ wtp,
                                          short* __restrict__ Bwb, short* __restrict__ catb,
                                          short* __restrict__ Cwb) {
  const int b = blockIdx.x;
  if (b < 512) {  // wh[row] = dot(W[row,:], h)
    const int lane = threadIdx.x & 63, wave = threadIdx.x >> 6;
    const int row = b * 4 + wave;
    const float* wr = W + (size_t)row * H_DIM;
    float s = 0.f;
#pragma unroll
    for (int it = 0; it < 8; it++) {
      int k = it * 256 + lane * 4;
      float4 a = *(const float4*)(wr + k);
      float4 hv = *(const float4*)(h + k);
      s += a.x * hv.x + a.y * hv.y + a.z * hv.z + a.w * hv.w;
    }
#pragma unroll
    for (int off = 32; off > 0; off >>= 1) s += __shfl_down(s, off);
    if (lane == 0) wh[row] = s;
  } else if (b < 768) {  // wtp[rowg][k] = sum over 64-row chunk of W[i][k]*h[i]
    const int e = b - 512;
    const int colg = e & 7, rowg = e >> 3;
    const int k = colg * 256 + threadIdx.x;
    float s = 0.f;
    const float* base = W + (size_t)rowg * 64 * H_DIM + k;
#pragma unroll 8
    for (int i = 0; i < 64; i++) s += base[(size_t)i * H_DIM] * h[rowg * 64 + i];
    wtp[rowg * H_DIM + k] = s;
  } else {  // Bw, cat(du,u), Cw -> bf16
    for (int g = (b - 768) * 256 + threadIdx.x; g < NTOT; g += 256 * 256) {
      if (g < NB) {
        int e = g * 8;
        *(int4*)(Bwb + e) = pack8(*(const float4*)(Bw + e), *(const float4*)(Bw + e + 4));
      } else if (g < NB + NCAT) {
        int g2 = g - NB;
        int row = g2 / 192, c = g2 - row * 192;  // 192 granules per 1536-wide row
        const float* src = (c < 64) ? du + (size_t)row * DU_DIM + c * 8
                                    : u + (size_t)row * U_DIM + (c - 64) * 8;
        *(int4*)(catb + (size_t)row * K_CAT + c * 8) =
            pack8(*(const float4*)src, *(const float4*)(src + 4));
      } else {
        int e = (g - NB - NCAT) * 8;
        *(int4*)(Cwb + e) = pack8(*(const float4*)(Cw + e), *(const float4*)(Cw + e + 4));
      }
    }
  }
}

#define MFMA __builtin_amdgcn_mfma_f32_16x16x32_bf16

// ---------------- K2: 1024 blocks, 32x64 tiles: bb = bf16(rec + DELTA*(catb @ Bwb^T)) ----------------
// 2-phase double-buffered LDS, global_load_lds staging, both-sides XOR granule swizzle.
__global__ __launch_bounds__(256) void k2(const short* __restrict__ catb, const short* __restrict__ Bwb,
                                          const float* __restrict__ h, const float* __restrict__ wh,
                                          const float* __restrict__ wtp, short* __restrict__ bb) {
  __shared__ __align__(16) short lds[2 * 6144];  // per buf: A 32x64 (2048) + B 64x64 (4096)
  __shared__ float recf[64];
  const int tid = threadIdx.x;
  const int lane = tid & 63, wave = tid >> 6;
  const int wm = wave >> 1, wn = wave & 1;
  const int mt = blockIdx.x >> 5, nt = blockIdx.x & 31;
  const int row0 = mt * 32, col0 = nt * 64;
  // staging: thread t owns granule (r=t>>3, g=t&7); source granule pre-swizzled g^(r&7).
  const int rA = tid >> 3, gA = tid & 7;
  const int sA = (gA ^ (rA & 7)) * 8;  // shorts offset inside the 64-short K-chunk; (r+32)&7==r&7
  const short* srcA  = catb + (size_t)(row0 + rA) * K_CAT + sA;
  const short* srcB1 = Bwb + (size_t)(col0 + rA) * K_CAT + sA;
  const short* srcB2 = Bwb + (size_t)(col0 + 32 + rA) * K_CAT + sA;
  const int NT = K_CAT / 64;
  const int rm = lane & 15, quad = lane >> 4;
  f32x4 acc[2] = {};
  stage16(srcA,  lds + tid * 8);
  stage16(srcB1, lds + 2048 + tid * 8);
  stage16(srcB2, lds + 4096 + tid * 8);
  __syncthreads();
  const int ra = wm * 16 + rm;
  const int rb0 = wn * 32 + rm, rb1 = wn * 32 + 16 + rm;
  const int oa = ra * 64, ob0 = rb0 * 64, ob1 = rb1 * 64;
  const int xa = (ra & 7), xb0 = (rb0 & 7), xb1 = (rb1 & 7);
  for (int kt = 0; kt < NT; kt++) {
    const int cur = kt & 1;
    if (kt + 1 < NT) {
      const int o = (kt + 1) * 64;
      short* nb = lds + (cur ^ 1) * 6144;
      stage16(srcA + o,  nb + tid * 8);
      stage16(srcB1 + o, nb + 2048 + tid * 8);
      stage16(srcB2 + o, nb + 4096 + tid * 8);
    }
    const short* Ac = lds + cur * 6144;
    const short* Bc = Ac + 2048;
#pragma unroll
    for (int ks = 0; ks < 2; ks++) {
      const int kg = ks * 4 + quad;
      bf16x8f af  = *(const bf16x8f*)&Ac[oa + ((kg ^ xa) << 3)];
      bf16x8f bf0 = *(const bf16x8f*)&Bc[ob0 + ((kg ^ xb0) << 3)];
      bf16x8f bf1 = *(const bf16x8f*)&Bc[ob1 + ((kg ^ xb1) << 3)];
      acc[0] = MFMA(af, bf0, acc[0], 0, 0, 0);
      acc[1] = MFMA(af, bf1, acc[1], 0, 0, 0);
    }
    if (kt + 1 < NT) __syncthreads();  // drains vmcnt (stage) + lgkm; 2-phase per T3-minimum
  }
  if (tid < 64) {  // rec[c] = h[c] + 0.005*(wh[c] - sum_p wtp[p][c])
    int gc = col0 + tid;
    float s = 0.f;
#pragma unroll
    for (int p = 0; p < 32; p++) s += wtp[p * H_DIM + gc];
    recf[tid] = h[gc] + 0.005f * (wh[gc] - s);
  }
  __syncthreads();
#pragma unroll
  for (int j = 0; j < 2; j++) {
    int gc = col0 + wn * 32 + 16 * j + rm;
#pragma unroll
    for (int r = 0; r < 4; r++) {
      int gr = row0 + wm * 16 + quad * 4 + r;
      bb[(size_t)gr * H_DIM + gc] = f2bs(recf[gc - col0] + DELTA_F * acc[j][r]);
    }
  }
}

// ---------------- K3: 512 blocks, 32x32 tiles: y = bb @ Cwb^T (f32 out) ----------------
__global__ __launch_bounds__(256) void k3(const short* __restrict__ A, const short* __restrict__ B,
                                          float* __restrict__ y) {
  __shared__ __align__(16) short lds[2 * 4096];  // per buf: A 32x64 (2048) + B 32x64 (2048)
  const int tid = threadIdx.x;
  const int lane = tid & 63, wave = tid >> 6;
  const int wm = wave >> 1, wn = wave & 1;
  const int mt = blockIdx.x >> 5, nt = blockIdx.x & 31;
  const int row0 = mt * 32, col0 = nt * 32;
  const int rA = tid >> 3, gA = tid & 7;
  const int sA = (gA ^ (rA & 7)) * 8;
  const short* srcA = A + (size_t)(row0 + rA) * H_DIM + sA;
  const short* srcB = B + (size_t)(col0 + rA) * H_DIM + sA;
  const int NT = H_DIM / 64;
  const int rm = lane & 15, quad = lane >> 4;
  f32x4 acc = {};
  stage16(srcA, lds + tid * 8);
  stage16(srcB, lds + 2048 + tid * 8);
  __syncthreads();
  const int ra = wm * 16 + rm, rb = wn * 16 + rm;
  const int oa = ra * 64, ob = rb * 64;
  const int xa = (ra & 7), xb = (rb & 7);
  for (int kt = 0; kt < NT; kt++) {
    const int cur = kt & 1;
    if (kt + 1 < NT) {
      const int o = (kt + 1) * 64;
      short* nb = lds + (cur ^ 1) * 4096;
      stage16(srcA + o, nb + tid * 8);
      stage16(srcB + o, nb + 2048 + tid * 8);
    }
    const short* Ac = lds + cur * 4096;
    const short* Bc = Ac + 2048;
#pragma unroll
    for (int ks = 0; ks < 2; ks++) {
      const int kg = ks * 4 + quad;
      bf16x8f af = *(const bf16x8f*)&Ac[oa + ((kg ^ xa) << 3)];
      bf16x8f bf = *(const bf16x8f*)&Bc[ob + ((kg ^ xb) << 3)];
      acc = MFMA(af, bf, acc, 0, 0, 0);
    }
    if (kt + 1 < NT) __syncthreads();
  }
  int gc = col0 + wn * 16 + rm;
#pragma unroll
  for (int r = 0; r < 4; r++) {
    int gr = row0 + wm * 16 + quad * 4 + r;
    y[(size_t)gr * Y_DIM + gc] = acc[r];
  }
}

extern "C" void kernel_launch(void* const* d_in, const int* in_sizes, int n_in,
                              void* d_out, int out_size, void* d_ws, size_t ws_size,
                              hipStream_t stream) {
  const float* u  = (const float*)d_in[0];
  const float* du = (const float*)d_in[1];
  const float* W  = (const float*)d_in[2];
  const float* Bw = (const float*)d_in[3];
  const float* Cw = (const float*)d_in[4];
  const float* h  = (const float*)d_in[5];
  float* y = (float*)d_out;

  char* w = (char*)d_ws;
  size_t off = 0;
  short* Bwb  = (short*)(w + off); off += (size_t)H_DIM * K_CAT * sizeof(short);  // 6 MB
  short* Cwb  = (short*)(w + off); off += (size_t)Y_DIM * H_DIM * sizeof(short);  // 4 MB
  short* bb   = (short*)(w + off); off += (size_t)B_SZ * H_DIM * sizeof(short);   // 2 MB
  short* catb = (short*)(w + off); off += (size_t)B_SZ * K_CAT * sizeof(short);   // 1.5 MB
  float* wh   = (float*)(w + off); off += H_DIM * sizeof(float);
  float* wtp  = (float*)(w + off); off += 32 * H_DIM * sizeof(float);
  if (ws_size < off) return;

  k1<<<1024, 256, 0, stream>>>(W, h, Bw, du, u, Cw, wh, wtp, Bwb, catb, Cwb);
  k2<<<1024, 256, 0, stream>>>(catb, Bwb, h, wh, wtp, bb);
  k3<<<512, 256, 0, stream>>>(bb, Cwb, y);
}